// Round 5
// baseline (312.130 us; speedup 1.0000x reference)
//
#include <hip/hip_runtime.h>

// Problem constants
#define KCB   1024      // codebook size
#define DCV   64        // code dim
#define HWN   4096      // H*W
#define CHW   262144    // DCV*HWN per batch
#define NTOT  131072    // 32*HWN

// Output offsets (floats), concatenated in reference return order
#define O_ZQ   0
#define O_IDX  8388608
#define O_LOSS 8519680
#define O_NE   8519681
#define O_NCS  8585217
#define O_NEA  8586241

// Workspace byte offsets — TOTAL FOOTPRINT 925,952 B < 1 MiB (ws limit; round-3
// failure was ws overflow corrupting the harness's pristine input copy).
#define W_LOSS  0                 // 8 B   double
#define W_CTR   64                // 4 B   int
#define W_E2    256               // 4 KB
#define W_SM    4352              // 4 KB
#define W_HIT   8448              // 128 KB bf16-hi codebook [q][code][8]
#define W_LOT   139520            // 128 KB bf16-lo codebook
#define W_PARTC 270592            // 128 KB per-batch count partials
#define W_RLIST 401664            // 512 KB refine list (cap NTOT)
// end = 925952

// hi/lo bf16 split error budget (lo*lo term + f32 MFMA accum + e2 f32) is
// <~1e-3 worst case on the dist scale; 0.015 is >10x margin.
#define MARGIN 0.015f

typedef __attribute__((ext_vector_type(8))) short short8v;
typedef __attribute__((ext_vector_type(4))) float f32x4;

__device__ __forceinline__ unsigned short rne16(float f) {
    unsigned u = __float_as_uint(f);
    unsigned r = (u + 0x7FFFu + ((u >> 16) & 1u)) >> 16;  // RNE to bf16 bits
    return (unsigned short)r;
}

// ---------------------------------------------------------------------------
// K0: init NEA = 0.99*ea; e2 = ||e||^2; bf16 hi/lo codebook in fragment
// layout hiT/loT[q][code][8] (q = k/8); zero scalars.
// ---------------------------------------------------------------------------
__global__ __launch_bounds__(256) void k_init(
    const float* __restrict__ emb, const float* __restrict__ ea,
    float* __restrict__ out, float* __restrict__ e2,
    short* __restrict__ hiT, short* __restrict__ loT,
    double* __restrict__ loss, int* __restrict__ ctr)
{
    int j = blockIdx.x * 256 + threadIdx.x;   // 0..65535
    out[O_NEA + j] = 0.99f * ea[j];
    if (j < KCB) {
        const float* er = emb + j * DCV;
        float s = 0.f;
        #pragma unroll
        for (int d = 0; d < DCV; ++d) { float v = er[d]; s = fmaf(v, v, s); }
        e2[j] = s;
    }
    if (j < 8192) {
        int code = j >> 3, q = j & 7;
        const float* src = emb + code * DCV + q * 8;
        short8v h, l;
        #pragma unroll
        for (int t = 0; t < 8; ++t) {
            float x = src[t];
            unsigned short hb = rne16(x);
            float xh = __uint_as_float(((unsigned)hb) << 16);
            h[t] = (short)hb;
            l[t] = (short)rne16(x - xh);
        }
        *(short8v*)(hiT + (size_t)(q * KCB + code) * 8) = h;
        *(short8v*)(loT + (size_t)(q * KCB + code) * 8) = l;
    }
    if (j == 0) { *loss = 0.0; *ctr = 0; }
}

// ---------------------------------------------------------------------------
// K1: MFMA distance argmin + FUSED z_q/loss epilogue. Block = 128 rows
// (4 waves x 32 rows). 128-code LDS chunks; 12 mfma per 16-code subchunk
// (hi*hi, hi*lo, lo*hi). Near-ties (gap < MARGIN) flagged for fp64 refine.
// Epilogue: per-row best broadcast via LDS, gather emb row, write z_q_st,
// accumulate commitment-loss partials (x reconstructed as hi+lo, err ~7e-6).
// ---------------------------------------------------------------------------
__global__ __launch_bounds__(256, 4) void k_dist(
    const float* __restrict__ ze, const float* __restrict__ emb,
    const short* __restrict__ hiT, const short* __restrict__ loT,
    const float* __restrict__ e2g, float* __restrict__ out,
    int* __restrict__ ctr, int* __restrict__ rlist, double* __restrict__ loss)
{
    __shared__ short ldsH[8 * 128 * 8];   // 16 KB
    __shared__ short ldsL[8 * 128 * 8];   // 16 KB
    __shared__ float e2s[KCB];            // 4 KB
    __shared__ int   bestSh[4][32];
    __shared__ float wsum[4];

    int tid  = threadIdx.x;
    int lane = tid & 63, w = tid >> 6;
    int g = lane >> 4, c = lane & 15;

    for (int i = tid; i < KCB; i += 256) e2s[i] = e2g[i];

    // A-fragments: row = lane&15, k = kh*32 + 8*(lane>>4) + j (same bijection as B)
    int rowbase = blockIdx.x * 128 + w * 32;
    short8v ahi[2][2], alo[2][2];
    #pragma unroll
    for (int t = 0; t < 2; ++t) {
        int n = rowbase + t * 16 + c;
        const float* base = ze + (size_t)(n >> 12) * CHW + (n & 4095);
        #pragma unroll
        for (int kh = 0; kh < 2; ++kh) {
            #pragma unroll
            for (int j = 0; j < 8; ++j) {
                int k = kh * 32 + g * 8 + j;
                float x = base[(size_t)k * HWN];
                unsigned short hb = rne16(x);
                float xh = __uint_as_float(((unsigned)hb) << 16);
                ahi[t][kh][j] = (short)hb;
                alo[t][kh][j] = (short)rne16(x - xh);
            }
        }
    }

    float best[8], second[8];
    int   bidx[8];
    #pragma unroll
    for (int i = 0; i < 8; ++i) { best[i] = 3.4e38f; second[i] = 3.4e38f; bidx[i] = 0; }

    for (int ch = 0; ch < 8; ++ch) {
        __syncthreads();
        #pragma unroll
        for (int r = 0; r < 8; ++r) {
            int u = r * 256 + tid;        // 0..2047 16B units
            int arr = u >> 10;
            int rest = u & 1023;          // q*128 + lc
            int q = rest >> 7, lc = rest & 127;
            const short* s = (arr ? loT : hiT) + (size_t)(q * KCB + ch * 128 + lc) * 8;
            short* d = (arr ? ldsL : ldsH) + rest * 8;
            *(short8v*)d = *(const short8v*)s;
        }
        __syncthreads();

        #pragma unroll 1
        for (int sub = 0; sub < 8; ++sub) {
            int boff = (sub * 16 + c) * 8;
            short8v bh0 = *(const short8v*)&ldsH[(g * 128) * 8 + boff];
            short8v bh1 = *(const short8v*)&ldsH[((4 + g) * 128) * 8 + boff];
            short8v bl0 = *(const short8v*)&ldsL[(g * 128) * 8 + boff];
            short8v bl1 = *(const short8v*)&ldsL[((4 + g) * 128) * 8 + boff];

            f32x4 a0 = {0.f, 0.f, 0.f, 0.f}, a1 = {0.f, 0.f, 0.f, 0.f};
            a0 = __builtin_amdgcn_mfma_f32_16x16x32_bf16(ahi[0][0], bh0, a0, 0, 0, 0);
            a1 = __builtin_amdgcn_mfma_f32_16x16x32_bf16(ahi[1][0], bh0, a1, 0, 0, 0);
            a0 = __builtin_amdgcn_mfma_f32_16x16x32_bf16(ahi[0][1], bh1, a0, 0, 0, 0);
            a1 = __builtin_amdgcn_mfma_f32_16x16x32_bf16(ahi[1][1], bh1, a1, 0, 0, 0);
            a0 = __builtin_amdgcn_mfma_f32_16x16x32_bf16(ahi[0][0], bl0, a0, 0, 0, 0);
            a1 = __builtin_amdgcn_mfma_f32_16x16x32_bf16(ahi[1][0], bl0, a1, 0, 0, 0);
            a0 = __builtin_amdgcn_mfma_f32_16x16x32_bf16(ahi[0][1], bl1, a0, 0, 0, 0);
            a1 = __builtin_amdgcn_mfma_f32_16x16x32_bf16(ahi[1][1], bl1, a1, 0, 0, 0);
            a0 = __builtin_amdgcn_mfma_f32_16x16x32_bf16(alo[0][0], bh0, a0, 0, 0, 0);
            a1 = __builtin_amdgcn_mfma_f32_16x16x32_bf16(alo[1][0], bh0, a1, 0, 0, 0);
            a0 = __builtin_amdgcn_mfma_f32_16x16x32_bf16(alo[0][1], bh1, a0, 0, 0, 0);
            a1 = __builtin_amdgcn_mfma_f32_16x16x32_bf16(alo[1][1], bh1, a1, 0, 0, 0);

            float e2v = e2s[ch * 128 + sub * 16 + c];
            int  code = ch * 128 + sub * 16 + c;
            #pragma unroll
            for (int t = 0; t < 2; ++t) {
                f32x4 av = t ? a1 : a0;
                #pragma unroll
                for (int r = 0; r < 4; ++r) {
                    int i = t * 4 + r;
                    float s = fmaf(-2.f, av[r], e2v);   // dist - x^2 (row-const drop)
                    bool lb = s < best[i];
                    float m = lb ? best[i] : s;
                    second[i] = fminf(second[i], m);
                    best[i]   = fminf(best[i], s);
                    bidx[i]   = lb ? code : bidx[i];
                }
            }
        }
    }

    #pragma unroll
    for (int i = 0; i < 8; ++i) {
        float b = best[i], s2 = second[i];
        int bi = bidx[i];
        #pragma unroll
        for (int m = 1; m < 16; m <<= 1) {
            float ob = __shfl_xor(b, m, 64);
            float os = __shfl_xor(s2, m, 64);
            int   oi = __shfl_xor(bi, m, 64);
            float ns = fminf(fmaxf(b, ob), fminf(s2, os));
            bi = (ob < b || (ob == b && oi < bi)) ? oi : bi;
            b  = fminf(b, ob);
            s2 = ns;
        }
        if (c == 0) {
            int t = i >> 2, r = i & 3;
            int rw = t * 16 + g * 4 + r;
            int n = rowbase + rw;
            out[O_IDX + n] = (float)bi;
            bestSh[w][rw] = bi;
            if (s2 - b < MARGIN) { int p = atomicAdd(ctr, 1); rlist[p] = n; }
        }
    }
    __syncthreads();

    // ---- fused z_q_st write + commitment-loss partial ----
    float lp = 0.f;
    #pragma unroll
    for (int t = 0; t < 2; ++t) {
        int rw = t * 16 + c;
        int n = rowbase + rw;
        int bsel = bestSh[w][rw];
        const float* erow = emb + bsel * DCV;
        float* zq = out + O_ZQ + (size_t)(n >> 12) * CHW + (n & 4095);
        #pragma unroll
        for (int kh = 0; kh < 2; ++kh) {
            int d0 = kh * 32 + g * 8;
            float4 e0 = *(const float4*)&erow[d0];
            float4 e1 = *(const float4*)&erow[d0 + 4];
            float ev[8] = {e0.x, e0.y, e0.z, e0.w, e1.x, e1.y, e1.z, e1.w};
            #pragma unroll
            for (int j = 0; j < 8; ++j) {
                float xh = __uint_as_float(((unsigned)(unsigned short)ahi[t][kh][j]) << 16);
                float xl = __uint_as_float(((unsigned)(unsigned short)alo[t][kh][j]) << 16);
                float xv = xh + xl;                 // x to ~7e-6 rel
                float er = ev[j];
                float df = xv - er;
                lp = fmaf(df, df, lp);
                zq[(size_t)(d0 + j) * HWN] = xv + (er - xv);  // straight-through rounding
            }
        }
    }
    #pragma unroll
    for (int off = 32; off > 0; off >>= 1) lp += __shfl_down(lp, off, 64);
    if (lane == 0) wsum[w] = lp;
    __syncthreads();
    if (tid == 0) {
        double s = (double)wsum[0] + wsum[1] + wsum[2] + wsum[3];
        atomicAdd(loss, s);
    }
}

// ---------------------------------------------------------------------------
// K2: fp64 exact argmin for flagged near-ties. One wave per candidate.
// On index change: rewrite idx + z_q row, adjust loss by exact fp64 delta.
// ---------------------------------------------------------------------------
__global__ __launch_bounds__(256) void k_refine(
    const float* __restrict__ ze, const float* __restrict__ emb,
    float* __restrict__ out, const int* __restrict__ ctr,
    const int* __restrict__ rlist, double* __restrict__ loss)
{
    int lane = threadIdx.x & 63;
    int gw   = (blockIdx.x * blockDim.x + threadIdx.x) >> 6;
    int nw   = (gridDim.x * blockDim.x) >> 6;
    int cnt  = *ctr;

    for (int i = gw; i < cnt; i += nw) {
        int n    = rlist[i];
        int oldi = (int)out[O_IDX + n];
        const float* zp = ze + (size_t)(n >> 12) * CHW + (n & 4095);
        float x[DCV];
        #pragma unroll
        for (int d = 0; d < DCV; ++d) x[d] = zp[(size_t)d * HWN];  // uniform -> broadcast

        double bd = 1e300, dold = -1e300;
        int    bi = 0;
        #pragma unroll 1
        for (int cc = 0; cc < KCB / 64; ++cc) {
            int k = cc * 64 + lane;
            const float4* eb4 = (const float4*)(emb + k * DCV);
            double a0 = 0.0, a1 = 0.0;
            #pragma unroll
            for (int q = 0; q < DCV / 4; ++q) {
                float4 v = eb4[q];
                double d0 = (double)x[q * 4 + 0] - (double)v.x;
                double d1 = (double)x[q * 4 + 1] - (double)v.y;
                double d2 = (double)x[q * 4 + 2] - (double)v.z;
                double d3 = (double)x[q * 4 + 3] - (double)v.w;
                a0 = fma(d0, d0, a0); a1 = fma(d1, d1, a1);
                a0 = fma(d2, d2, a0); a1 = fma(d3, d3, a1);
            }
            double dist = a0 + a1;
            if (k == oldi) dold = dist;
            if (dist < bd || (dist == bd && k < bi)) { bd = dist; bi = k; }
        }
        #pragma unroll
        for (int off = 32; off > 0; off >>= 1) {
            double od = __shfl_xor(bd, off, 64);
            int    oi = __shfl_xor(bi, off, 64);
            double oo = __shfl_xor(dold, off, 64);
            if (od < bd || (od == bd && oi < bi)) { bd = od; bi = oi; }
            dold = fmax(dold, oo);
        }
        if (bi != oldi) {   // lane-uniform after butterfly
            if (lane == 0) {
                out[O_IDX + n] = (float)bi;
                atomicAdd(loss, bd - dold);
            }
            float e  = emb[bi * DCV + lane];
            float xv = x[lane];
            float* zq = out + O_ZQ + (size_t)(n >> 12) * CHW + (n & 4095);
            zq[(size_t)lane * HWN] = xv + (e - xv);
        }
    }
}

// ---------------------------------------------------------------------------
// K3: segment-sum partials in LDS (acc[idx*8+i]: 8 banks per thread burst);
// atomic flush 0.01*dw into NEA. gidx==0 blocks also write count partials.
// ---------------------------------------------------------------------------
__global__ __launch_bounds__(256) void k_dw_part(
    const float* __restrict__ ze, const float* __restrict__ outIdx,
    float* __restrict__ partc, float* __restrict__ out)
{
    int gidx = blockIdx.x >> 5, b = blockIdx.x & 31;
    __shared__ float acc[8 * KCB];   // [code][dim8]
    __shared__ float cnt[KCB];
    for (int i = threadIdx.x; i < 8 * KCB; i += 256) acc[i] = 0.f;
    if (gidx == 0) for (int i = threadIdx.x; i < KCB; i += 256) cnt[i] = 0.f;
    __syncthreads();

    const float* zp  = ze + (size_t)b * CHW + (size_t)gidx * 8 * HWN;
    const float* ipf = outIdx + b * HWN;
    for (int hw = threadIdx.x; hw < HWN; hw += 256) {
        int idx = (int)ipf[hw];
        #pragma unroll
        for (int i = 0; i < 8; ++i) atomicAdd(&acc[idx * 8 + i], zp[(size_t)i * HWN + hw]);
        if (gidx == 0) atomicAdd(&cnt[idx], 1.f);
    }
    __syncthreads();

    for (int j = threadIdx.x; j < 8192; j += 256) {
        float v = acc[j];
        if (v != 0.f) atomicAdd(&out[O_NEA + (j >> 3) * DCV + gidx * 8 + (j & 7)], 0.01f * v);
    }
    if (gidx == 0)
        for (int k = threadIdx.x; k < KCB; k += 256) partc[b * KCB + k] = cnt[k];
}

// ---------------------------------------------------------------------------
// K4: counts EMA + n + smoothed denom + loss scalar
// ---------------------------------------------------------------------------
__global__ __launch_bounds__(1024) void k_stats(
    const float* __restrict__ cs, const float* __restrict__ partc,
    float* __restrict__ out, float* __restrict__ sm,
    const double* __restrict__ loss)
{
    int k = threadIdx.x;
    float csum = 0.f;
    #pragma unroll
    for (int b = 0; b < 32; ++b) csum += partc[b * KCB + k];
    float ncs = fmaf(0.01f, csum, 0.99f * cs[k]);
    out[O_NCS + k] = ncs;

    __shared__ float red[KCB];
    red[k] = ncs;
    __syncthreads();
    for (int s = 512; s > 0; s >>= 1) {
        if (k < s) red[k] += red[k + s];
        __syncthreads();
    }
    float n = red[0];
    sm[k] = (ncs + 1e-5f) / (n + (float)KCB * 1e-5f) * n;
    if (k == 0) out[O_LOSS] = (float)(0.25 * (*loss) / (double)(NTOT * DCV));
}

// K5: new_embedding = new_embed_avg / smoothed[k]
__global__ __launch_bounds__(256) void k_embed(
    float* __restrict__ out, const float* __restrict__ sm)
{
    int j = blockIdx.x * 256 + threadIdx.x;
    out[O_NE + j] = out[O_NEA + j] / sm[j >> 6];
}

// ---------------------------------------------------------------------------
extern "C" void kernel_launch(void* const* d_in, const int* in_sizes, int n_in,
                              void* d_out, int out_size, void* d_ws, size_t ws_size,
                              hipStream_t stream)
{
    const float* ze  = (const float*)d_in[0];
    const float* emb = (const float*)d_in[1];
    const float* cs  = (const float*)d_in[2];
    const float* ea  = (const float*)d_in[3];
    float* out = (float*)d_out;

    char*   w     = (char*)d_ws;
    double* loss  = (double*)(w + W_LOSS);
    int*    ctr   = (int*)(w + W_CTR);
    float*  e2    = (float*)(w + W_E2);
    float*  sm    = (float*)(w + W_SM);
    short*  hiT   = (short*)(w + W_HIT);
    short*  loT   = (short*)(w + W_LOT);
    float*  partc = (float*)(w + W_PARTC);
    int*    rlist = (int*)(w + W_RLIST);

    k_init   <<<256, 256, 0, stream>>>(emb, ea, out, e2, hiT, loT, loss, ctr);
    k_dist   <<<1024, 256, 0, stream>>>(ze, emb, hiT, loT, e2, out, ctr, rlist, loss);
    k_refine <<<256, 256, 0, stream>>>(ze, emb, out, ctr, rlist, loss);
    k_dw_part<<<256, 256, 0, stream>>>(ze, (const float*)(out + O_IDX), partc, out);
    k_stats  <<<1, 1024, 0, stream>>>(cs, partc, out, sm, loss);
    k_embed  <<<256, 256, 0, stream>>>(out, sm);
}

// Round 6
// 268.874 us; speedup vs baseline: 1.1609x; 1.1609x over previous
//
#include <hip/hip_runtime.h>

// Problem constants
#define KCB   1024      // codebook size
#define DCV   64        // code dim
#define HWN   4096      // H*W
#define CHW   262144    // DCV*HWN per batch
#define NTOT  131072    // 32*HWN

// Output offsets (floats), concatenated in reference return order
#define O_ZQ   0
#define O_IDX  8388608
#define O_LOSS 8519680
#define O_NE   8519681
#define O_NCS  8585217
#define O_NEA  8586241

// Workspace byte offsets — TOTAL 794,880 B < 1 MiB (hard limit: round-3 ws
// overflow corrupted the harness's pristine input copy).
#define W_LOSS  0                 // 8 B   double
#define W_CTR   64                // 4 B   int
#define W_E2    256               // 4 KB
#define W_SM    4352              // 4 KB
#define W_HIT   8448              // 128 KB bf16-hi codebook [q][code][8]
#define W_LOT   139520            // 128 KB bf16-lo codebook
#define W_EMBT  270592            // 256 KB transposed codebook [d][code] f32
#define W_RLIST 532736            // 256 KB refine list (cap 65536)
// end = 794880

#define RCAP   65536
// hi/lo bf16 split worst-case dist error ~3e-3; 0.015 = 5x margin (validated r5)
#define MARGIN 0.015f

typedef __attribute__((ext_vector_type(8))) short short8v;
typedef __attribute__((ext_vector_type(4))) float f32x4;

__device__ __forceinline__ unsigned short rne16(float f) {
    unsigned u = __float_as_uint(f);
    unsigned r = (u + 0x7FFFu + ((u >> 16) & 1u)) >> 16;  // RNE to bf16 bits
    return (unsigned short)r;
}

// ---------------------------------------------------------------------------
// K0: init NEA=0.99*ea, NCS=0.99*cs; e2=||e||^2; bf16 hi/lo codebook in
// fragment layout; transposed f32 codebook embT[d][code]; zero scalars.
// ---------------------------------------------------------------------------
__global__ __launch_bounds__(256) void k_init(
    const float* __restrict__ emb, const float* __restrict__ ea,
    const float* __restrict__ cs, float* __restrict__ out,
    float* __restrict__ e2, short* __restrict__ hiT, short* __restrict__ loT,
    float* __restrict__ embT, double* __restrict__ loss, int* __restrict__ ctr)
{
    int j = blockIdx.x * 256 + threadIdx.x;   // 0..65535
    out[O_NEA + j] = 0.99f * ea[j];

    // embT[d*1024+code] = emb[code*64+d]; j = code*64+d -> coalesced read
    {
        int code = j >> 6, d = j & 63;
        embT[d * KCB + code] = emb[j];
    }
    if (j < KCB) {
        out[O_NCS + j] = 0.99f * cs[j];
        const float* er = emb + j * DCV;
        float s = 0.f;
        #pragma unroll
        for (int d = 0; d < DCV; ++d) { float v = er[d]; s = fmaf(v, v, s); }
        e2[j] = s;
    }
    if (j < 8192) {
        int code = j >> 3, q = j & 7;
        const float* src = emb + code * DCV + q * 8;
        short8v h, l;
        #pragma unroll
        for (int t = 0; t < 8; ++t) {
            float x = src[t];
            unsigned short hb = rne16(x);
            float xh = __uint_as_float(((unsigned)hb) << 16);
            h[t] = (short)hb;
            l[t] = (short)rne16(x - xh);
        }
        *(short8v*)(hiT + (size_t)(q * KCB + code) * 8) = h;
        *(short8v*)(loT + (size_t)(q * KCB + code) * 8) = l;
    }
    if (j == 0) { *loss = 0.0; *ctr = 0; }
}

// ---------------------------------------------------------------------------
// K1: MFMA distance argmin (round-4 proven form, 70us). Block = 128 rows
// (4 waves x 32). 128-code LDS chunks; 12 mfma per 16-code subchunk
// (hi*hi, hi*lo, lo*hi). Near-ties (gap < MARGIN) flagged for fp64 refine.
// ---------------------------------------------------------------------------
__global__ __launch_bounds__(256, 4) void k_dist(
    const float* __restrict__ ze, const short* __restrict__ hiT,
    const short* __restrict__ loT, const float* __restrict__ e2g,
    float* __restrict__ out, int* __restrict__ ctr, int* __restrict__ rlist)
{
    __shared__ short ldsH[8 * 128 * 8];   // 16 KB
    __shared__ short ldsL[8 * 128 * 8];   // 16 KB
    __shared__ float e2s[KCB];            // 4 KB

    int tid  = threadIdx.x;
    int lane = tid & 63, w = tid >> 6;
    int g = lane >> 4, c = lane & 15;

    for (int i = tid; i < KCB; i += 256) e2s[i] = e2g[i];

    // A-fragments: row = lane&15, k = kh*32 + 8*(lane>>4) + j (same bijection as B)
    int rowbase = blockIdx.x * 128 + w * 32;
    short8v ahi[2][2], alo[2][2];
    #pragma unroll
    for (int t = 0; t < 2; ++t) {
        int n = rowbase + t * 16 + c;
        const float* base = ze + (size_t)(n >> 12) * CHW + (n & 4095);
        #pragma unroll
        for (int kh = 0; kh < 2; ++kh) {
            #pragma unroll
            for (int j = 0; j < 8; ++j) {
                int k = kh * 32 + g * 8 + j;
                float x = base[(size_t)k * HWN];
                unsigned short hb = rne16(x);
                float xh = __uint_as_float(((unsigned)hb) << 16);
                ahi[t][kh][j] = (short)hb;
                alo[t][kh][j] = (short)rne16(x - xh);
            }
        }
    }

    float best[8], second[8];
    int   bidx[8];
    #pragma unroll
    for (int i = 0; i < 8; ++i) { best[i] = 3.4e38f; second[i] = 3.4e38f; bidx[i] = 0; }

    for (int ch = 0; ch < 8; ++ch) {
        __syncthreads();
        #pragma unroll
        for (int r = 0; r < 8; ++r) {
            int u = r * 256 + tid;        // 0..2047 16B units
            int arr = u >> 10;
            int rest = u & 1023;          // q*128 + lc
            int q = rest >> 7, lc = rest & 127;
            const short* s = (arr ? loT : hiT) + (size_t)(q * KCB + ch * 128 + lc) * 8;
            short* d = (arr ? ldsL : ldsH) + rest * 8;
            *(short8v*)d = *(const short8v*)s;
        }
        __syncthreads();

        #pragma unroll 1
        for (int sub = 0; sub < 8; ++sub) {
            int boff = (sub * 16 + c) * 8;
            short8v bh0 = *(const short8v*)&ldsH[(g * 128) * 8 + boff];
            short8v bh1 = *(const short8v*)&ldsH[((4 + g) * 128) * 8 + boff];
            short8v bl0 = *(const short8v*)&ldsL[(g * 128) * 8 + boff];
            short8v bl1 = *(const short8v*)&ldsL[((4 + g) * 128) * 8 + boff];

            f32x4 a0 = {0.f, 0.f, 0.f, 0.f}, a1 = {0.f, 0.f, 0.f, 0.f};
            a0 = __builtin_amdgcn_mfma_f32_16x16x32_bf16(ahi[0][0], bh0, a0, 0, 0, 0);
            a1 = __builtin_amdgcn_mfma_f32_16x16x32_bf16(ahi[1][0], bh0, a1, 0, 0, 0);
            a0 = __builtin_amdgcn_mfma_f32_16x16x32_bf16(ahi[0][1], bh1, a0, 0, 0, 0);
            a1 = __builtin_amdgcn_mfma_f32_16x16x32_bf16(ahi[1][1], bh1, a1, 0, 0, 0);
            a0 = __builtin_amdgcn_mfma_f32_16x16x32_bf16(ahi[0][0], bl0, a0, 0, 0, 0);
            a1 = __builtin_amdgcn_mfma_f32_16x16x32_bf16(ahi[1][0], bl0, a1, 0, 0, 0);
            a0 = __builtin_amdgcn_mfma_f32_16x16x32_bf16(ahi[0][1], bl1, a0, 0, 0, 0);
            a1 = __builtin_amdgcn_mfma_f32_16x16x32_bf16(ahi[1][1], bl1, a1, 0, 0, 0);
            a0 = __builtin_amdgcn_mfma_f32_16x16x32_bf16(alo[0][0], bh0, a0, 0, 0, 0);
            a1 = __builtin_amdgcn_mfma_f32_16x16x32_bf16(alo[1][0], bh0, a1, 0, 0, 0);
            a0 = __builtin_amdgcn_mfma_f32_16x16x32_bf16(alo[0][1], bh1, a0, 0, 0, 0);
            a1 = __builtin_amdgcn_mfma_f32_16x16x32_bf16(alo[1][1], bh1, a1, 0, 0, 0);

            float e2v = e2s[ch * 128 + sub * 16 + c];
            int  code = ch * 128 + sub * 16 + c;
            #pragma unroll
            for (int t = 0; t < 2; ++t) {
                f32x4 av = t ? a1 : a0;
                #pragma unroll
                for (int r = 0; r < 4; ++r) {
                    int i = t * 4 + r;
                    float s = fmaf(-2.f, av[r], e2v);   // dist - x^2 (row-const drop)
                    bool lb = s < best[i];
                    float m = lb ? best[i] : s;
                    second[i] = fminf(second[i], m);
                    best[i]   = fminf(best[i], s);
                    bidx[i]   = lb ? code : bidx[i];
                }
            }
        }
    }

    #pragma unroll
    for (int i = 0; i < 8; ++i) {
        float b = best[i], s2 = second[i];
        int bi = bidx[i];
        #pragma unroll
        for (int m = 1; m < 16; m <<= 1) {
            float ob = __shfl_xor(b, m, 64);
            float os = __shfl_xor(s2, m, 64);
            int   oi = __shfl_xor(bi, m, 64);
            float ns = fminf(fmaxf(b, ob), fminf(s2, os));
            bi = (ob < b || (ob == b && oi < bi)) ? oi : bi;
            b  = fminf(b, ob);
            s2 = ns;
        }
        if (c == 0) {
            int t = i >> 2, r = i & 3;
            int n = rowbase + t * 16 + g * 4 + r;
            out[O_IDX + n] = (float)bi;
            if (s2 - b < MARGIN) {
                int p = atomicAdd(ctr, 1);
                if (p < RCAP) rlist[p] = n;
            }
        }
    }
}

// ---------------------------------------------------------------------------
// K2: fp64 exact argmin for flagged near-ties; fixes index only (z_q/loss
// are computed downstream from final indices). One wave per candidate.
// ---------------------------------------------------------------------------
__global__ __launch_bounds__(256) void k_refine(
    const float* __restrict__ ze, const float* __restrict__ emb,
    float* __restrict__ out, const int* __restrict__ ctr,
    const int* __restrict__ rlist)
{
    int lane = threadIdx.x & 63;
    int gw   = (blockIdx.x * blockDim.x + threadIdx.x) >> 6;
    int nw   = (gridDim.x * blockDim.x) >> 6;
    int cnt  = *ctr;
    if (cnt > RCAP) cnt = RCAP;

    for (int i = gw; i < cnt; i += nw) {
        int n = rlist[i];
        const float* zp = ze + (size_t)(n >> 12) * CHW + (n & 4095);
        float x[DCV];
        #pragma unroll
        for (int d = 0; d < DCV; ++d) x[d] = zp[(size_t)d * HWN];  // uniform -> broadcast

        double bd = 1e300;
        int    bi = 0;
        #pragma unroll 1
        for (int cc = 0; cc < KCB / 64; ++cc) {
            int k = cc * 64 + lane;
            const float4* eb4 = (const float4*)(emb + k * DCV);
            double a0 = 0.0, a1 = 0.0;
            #pragma unroll
            for (int q = 0; q < DCV / 4; ++q) {
                float4 v = eb4[q];
                double d0 = (double)x[q * 4 + 0] - (double)v.x;
                double d1 = (double)x[q * 4 + 1] - (double)v.y;
                double d2 = (double)x[q * 4 + 2] - (double)v.z;
                double d3 = (double)x[q * 4 + 3] - (double)v.w;
                a0 = fma(d0, d0, a0); a1 = fma(d1, d1, a1);
                a0 = fma(d2, d2, a0); a1 = fma(d3, d3, a1);
            }
            double dist = a0 + a1;
            if (dist < bd || (dist == bd && k < bi)) { bd = dist; bi = k; }
        }
        #pragma unroll
        for (int off = 32; off > 0; off >>= 1) {
            double od = __shfl_xor(bd, off, 64);
            int    oi = __shfl_xor(bi, off, 64);
            if (od < bd || (od == bd && oi < bi)) { bd = od; bi = oi; }
        }
        if (lane == 0) out[O_IDX + n] = (float)bi;
    }
}

// ---------------------------------------------------------------------------
// K3: coalesced finalize. Thread <-> fixed hw; loop over d: z_e read and z_q
// write are hw-contiguous (1KB/instr per block); code values gathered from
// embT[d][code] (4KB row -> L1). Commitment-loss partials accumulated.
// ---------------------------------------------------------------------------
__global__ __launch_bounds__(256) void k_final(
    const float* __restrict__ ze, const float* __restrict__ embT,
    float* __restrict__ out, double* __restrict__ loss)
{
    int blk = blockIdx.x;            // 512 blocks: b = blk>>4, tile = blk&15
    int b   = blk >> 4;
    int hw  = (blk & 15) * 256 + threadIdx.x;
    int n   = b * HWN + hw;

    int myidx = (int)out[O_IDX + n];

    const float* zp = ze  + (size_t)b * CHW + hw;
    float*       zq = out + O_ZQ + (size_t)b * CHW + hw;

    float lp = 0.f;
    #pragma unroll 8
    for (int d = 0; d < DCV; ++d) {
        float x = zp[(size_t)d * HWN];
        float e = embT[d * KCB + myidx];
        float df = x - e;
        lp = fmaf(df, df, lp);
        zq[(size_t)d * HWN] = x + (e - x);  // straight-through f32 rounding
    }

    #pragma unroll
    for (int off = 32; off > 0; off >>= 1) lp += __shfl_down(lp, off, 64);

    __shared__ float wsum[4];
    int lane = threadIdx.x & 63, wid = threadIdx.x >> 6;
    if (lane == 0) wsum[wid] = lp;
    __syncthreads();
    if (threadIdx.x == 0) {
        double s = (double)wsum[0] + wsum[1] + wsum[2] + wsum[3];
        atomicAdd(loss, s);
    }
}

// ---------------------------------------------------------------------------
// K4: segment-sum partials in LDS (acc[idx*8+i]); atomic flush 0.01*dw into
// NEA. gidx==0 blocks also flush 0.01*counts into NCS (pre-inited 0.99*cs).
// ---------------------------------------------------------------------------
__global__ __launch_bounds__(256) void k_dw_part(
    const float* __restrict__ ze, const float* __restrict__ outIdx,
    float* __restrict__ out)
{
    int gidx = blockIdx.x >> 5, b = blockIdx.x & 31;
    __shared__ float acc[8 * KCB];   // [code][dim8]
    __shared__ float cnt[KCB];
    for (int i = threadIdx.x; i < 8 * KCB; i += 256) acc[i] = 0.f;
    if (gidx == 0) for (int i = threadIdx.x; i < KCB; i += 256) cnt[i] = 0.f;
    __syncthreads();

    const float* zp  = ze + (size_t)b * CHW + (size_t)gidx * 8 * HWN;
    const float* ipf = outIdx + b * HWN;
    for (int hw = threadIdx.x; hw < HWN; hw += 256) {
        int idx = (int)ipf[hw];
        #pragma unroll
        for (int i = 0; i < 8; ++i) atomicAdd(&acc[idx * 8 + i], zp[(size_t)i * HWN + hw]);
        if (gidx == 0) atomicAdd(&cnt[idx], 1.f);
    }
    __syncthreads();

    for (int j = threadIdx.x; j < 8192; j += 256) {
        float v = acc[j];
        if (v != 0.f) atomicAdd(&out[O_NEA + (j >> 3) * DCV + gidx * 8 + (j & 7)], 0.01f * v);
    }
    if (gidx == 0)
        for (int k = threadIdx.x; k < KCB; k += 256) {
            float cv = cnt[k];
            if (cv != 0.f) atomicAdd(&out[O_NCS + k], 0.01f * cv);
        }
}

// ---------------------------------------------------------------------------
// K5: n = sum(NCS); smoothed denom; loss scalar
// ---------------------------------------------------------------------------
__global__ __launch_bounds__(1024) void k_stats(
    float* __restrict__ out, float* __restrict__ sm,
    const double* __restrict__ loss)
{
    int k = threadIdx.x;
    float ncs = out[O_NCS + k];
    __shared__ float red[KCB];
    red[k] = ncs;
    __syncthreads();
    for (int s = 512; s > 0; s >>= 1) {
        if (k < s) red[k] += red[k + s];
        __syncthreads();
    }
    float n = red[0];
    sm[k] = (ncs + 1e-5f) / (n + (float)KCB * 1e-5f) * n;
    if (k == 0) out[O_LOSS] = (float)(0.25 * (*loss) / (double)(NTOT * DCV));
}

// K6: new_embedding = new_embed_avg / smoothed[k]
__global__ __launch_bounds__(256) void k_embed(
    float* __restrict__ out, const float* __restrict__ sm)
{
    int j = blockIdx.x * 256 + threadIdx.x;
    out[O_NE + j] = out[O_NEA + j] / sm[j >> 6];
}

// ---------------------------------------------------------------------------
extern "C" void kernel_launch(void* const* d_in, const int* in_sizes, int n_in,
                              void* d_out, int out_size, void* d_ws, size_t ws_size,
                              hipStream_t stream)
{
    const float* ze  = (const float*)d_in[0];
    const float* emb = (const float*)d_in[1];
    const float* cs  = (const float*)d_in[2];
    const float* ea  = (const float*)d_in[3];
    float* out = (float*)d_out;

    char*   w     = (char*)d_ws;
    double* loss  = (double*)(w + W_LOSS);
    int*    ctr   = (int*)(w + W_CTR);
    float*  e2    = (float*)(w + W_E2);
    float*  sm    = (float*)(w + W_SM);
    short*  hiT   = (short*)(w + W_HIT);
    short*  loT   = (short*)(w + W_LOT);
    float*  embT  = (float*)(w + W_EMBT);
    int*    rlist = (int*)(w + W_RLIST);

    k_init   <<<256, 256, 0, stream>>>(emb, ea, cs, out, e2, hiT, loT, embT, loss, ctr);
    k_dist   <<<1024, 256, 0, stream>>>(ze, hiT, loT, e2, out, ctr, rlist);
    k_refine <<<256, 256, 0, stream>>>(ze, emb, out, ctr, rlist);
    k_final  <<<512, 256, 0, stream>>>(ze, embT, out, loss);
    k_dw_part<<<256, 256, 0, stream>>>(ze, (const float*)(out + O_IDX), out);
    k_stats  <<<1, 1024, 0, stream>>>(out, sm, loss);
    k_embed  <<<256, 256, 0, stream>>>(out, sm);
}

// Round 7
// 247.639 us; speedup vs baseline: 1.2604x; 1.0857x over previous
//
#include <hip/hip_runtime.h>

// Problem constants
#define KCB   1024      // codebook size
#define DCV   64        // code dim
#define HWN   4096      // H*W
#define CHW   262144    // DCV*HWN per batch
#define NTOT  131072    // 32*HWN

// Output offsets (floats), concatenated in reference return order
#define O_ZQ   0
#define O_IDX  8388608
#define O_LOSS 8519680
#define O_NE   8519681
#define O_NCS  8585217
#define O_NEA  8586241

// Workspace byte offsets — TOTAL 794,880 B < 1 MiB (hard limit: round-3 ws
// overflow corrupted the harness's pristine input copy).
#define W_LOSS  0                 // 8 B   double
#define W_CTR   64                // 4 B   int
#define W_E2    256               // 4 KB
#define W_HIT   8448              // 128 KB bf16-hi codebook [q][code][8]
#define W_LOT   139520            // 128 KB bf16-lo codebook
#define W_EMBT  270592            // 256 KB transposed codebook [d][code] f32
#define W_RLIST 532736            // 256 KB refine list (cap 65536)
// end = 794880

#define RCAP   65536
// hi/lo bf16 split worst-case pairwise dist error <~1e-3; 0.01 = 10x margin
#define MARGIN 0.01f

typedef __attribute__((ext_vector_type(8))) short short8v;
typedef __attribute__((ext_vector_type(4))) float f32x4;

__device__ __forceinline__ unsigned short rne16(float f) {
    unsigned u = __float_as_uint(f);
    unsigned r = (u + 0x7FFFu + ((u >> 16) & 1u)) >> 16;  // RNE to bf16 bits
    return (unsigned short)r;
}

// ---------------------------------------------------------------------------
// K0: init NEA=0.99*ea, NCS=0.99*cs; e2=||e||^2; bf16 hi/lo codebook in
// fragment layout; transposed f32 codebook embT[d][code]; zero scalars.
// ---------------------------------------------------------------------------
__global__ __launch_bounds__(256) void k_init(
    const float* __restrict__ emb, const float* __restrict__ ea,
    const float* __restrict__ cs, float* __restrict__ out,
    float* __restrict__ e2, short* __restrict__ hiT, short* __restrict__ loT,
    float* __restrict__ embT, double* __restrict__ loss, int* __restrict__ ctr)
{
    int j = blockIdx.x * 256 + threadIdx.x;   // 0..65535
    out[O_NEA + j] = 0.99f * ea[j];

    // embT[d*1024+code] = emb[code*64+d]; j = code*64+d -> coalesced read
    {
        int code = j >> 6, d = j & 63;
        embT[d * KCB + code] = emb[j];
    }
    if (j < KCB) {
        out[O_NCS + j] = 0.99f * cs[j];
        const float* er = emb + j * DCV;
        float s = 0.f;
        #pragma unroll
        for (int d = 0; d < DCV; ++d) { float v = er[d]; s = fmaf(v, v, s); }
        e2[j] = s;
    }
    if (j < 8192) {
        int code = j >> 3, q = j & 7;
        const float* src = emb + code * DCV + q * 8;
        short8v h, l;
        #pragma unroll
        for (int t = 0; t < 8; ++t) {
            float x = src[t];
            unsigned short hb = rne16(x);
            float xh = __uint_as_float(((unsigned)hb) << 16);
            h[t] = (short)hb;
            l[t] = (short)rne16(x - xh);
        }
        *(short8v*)(hiT + (size_t)(q * KCB + code) * 8) = h;
        *(short8v*)(loT + (size_t)(q * KCB + code) * 8) = l;
    }
    if (j == 0) { *loss = 0.0; *ctr = 0; }
}

// ---------------------------------------------------------------------------
// K1: MFMA distance argmin. Block = 128 rows (4 waves x 32). 128-code LDS
// chunks; 12 mfma per 16-code subchunk (hi*hi, hi*lo, lo*hi). Near-ties
// (gap < MARGIN) flagged for fp64 refine.
// launch_bounds(256,2): r6 ran at VGPR_Count=60 (forced by min-waves=4),
// starving ~90 live regs -> AGPR bouncing inflated VALU. Cap 256 instead.
// ---------------------------------------------------------------------------
__global__ __launch_bounds__(256, 2) void k_dist(
    const float* __restrict__ ze, const short* __restrict__ hiT,
    const short* __restrict__ loT, const float* __restrict__ e2g,
    float* __restrict__ out, int* __restrict__ ctr, int* __restrict__ rlist)
{
    __shared__ short ldsH[8 * 128 * 8];   // 16 KB
    __shared__ short ldsL[8 * 128 * 8];   // 16 KB
    __shared__ float e2s[KCB];            // 4 KB

    int tid  = threadIdx.x;
    int lane = tid & 63, w = tid >> 6;
    int g = lane >> 4, c = lane & 15;

    for (int i = tid; i < KCB; i += 256) e2s[i] = e2g[i];

    // A-fragments: row = lane&15, k = kh*32 + 8*(lane>>4) + j (same bijection as B)
    int rowbase = blockIdx.x * 128 + w * 32;
    short8v ahi[2][2], alo[2][2];
    #pragma unroll
    for (int t = 0; t < 2; ++t) {
        int n = rowbase + t * 16 + c;
        const float* base = ze + (size_t)(n >> 12) * CHW + (n & 4095);
        #pragma unroll
        for (int kh = 0; kh < 2; ++kh) {
            #pragma unroll
            for (int j = 0; j < 8; ++j) {
                int k = kh * 32 + g * 8 + j;
                float x = base[(size_t)k * HWN];
                unsigned short hb = rne16(x);
                float xh = __uint_as_float(((unsigned)hb) << 16);
                ahi[t][kh][j] = (short)hb;
                alo[t][kh][j] = (short)rne16(x - xh);
            }
        }
    }

    float best[8], second[8];
    int   bidx[8];
    #pragma unroll
    for (int i = 0; i < 8; ++i) { best[i] = 3.4e38f; second[i] = 3.4e38f; bidx[i] = 0; }

    for (int ch = 0; ch < 8; ++ch) {
        __syncthreads();
        #pragma unroll
        for (int r = 0; r < 8; ++r) {
            int u = r * 256 + tid;        // 0..2047 16B units
            int arr = u >> 10;
            int rest = u & 1023;          // q*128 + lc
            int q = rest >> 7, lc = rest & 127;
            const short* s = (arr ? loT : hiT) + (size_t)(q * KCB + ch * 128 + lc) * 8;
            short* d = (arr ? ldsL : ldsH) + rest * 8;
            *(short8v*)d = *(const short8v*)s;
        }
        __syncthreads();

        #pragma unroll 1
        for (int sub = 0; sub < 8; ++sub) {
            int boff = (sub * 16 + c) * 8;
            short8v bh0 = *(const short8v*)&ldsH[(g * 128) * 8 + boff];
            short8v bh1 = *(const short8v*)&ldsH[((4 + g) * 128) * 8 + boff];
            short8v bl0 = *(const short8v*)&ldsL[(g * 128) * 8 + boff];
            short8v bl1 = *(const short8v*)&ldsL[((4 + g) * 128) * 8 + boff];

            f32x4 a0 = {0.f, 0.f, 0.f, 0.f}, a1 = {0.f, 0.f, 0.f, 0.f};
            a0 = __builtin_amdgcn_mfma_f32_16x16x32_bf16(ahi[0][0], bh0, a0, 0, 0, 0);
            a1 = __builtin_amdgcn_mfma_f32_16x16x32_bf16(ahi[1][0], bh0, a1, 0, 0, 0);
            a0 = __builtin_amdgcn_mfma_f32_16x16x32_bf16(ahi[0][1], bh1, a0, 0, 0, 0);
            a1 = __builtin_amdgcn_mfma_f32_16x16x32_bf16(ahi[1][1], bh1, a1, 0, 0, 0);
            a0 = __builtin_amdgcn_mfma_f32_16x16x32_bf16(ahi[0][0], bl0, a0, 0, 0, 0);
            a1 = __builtin_amdgcn_mfma_f32_16x16x32_bf16(ahi[1][0], bl0, a1, 0, 0, 0);
            a0 = __builtin_amdgcn_mfma_f32_16x16x32_bf16(ahi[0][1], bl1, a0, 0, 0, 0);
            a1 = __builtin_amdgcn_mfma_f32_16x16x32_bf16(ahi[1][1], bl1, a1, 0, 0, 0);
            a0 = __builtin_amdgcn_mfma_f32_16x16x32_bf16(alo[0][0], bh0, a0, 0, 0, 0);
            a1 = __builtin_amdgcn_mfma_f32_16x16x32_bf16(alo[1][0], bh0, a1, 0, 0, 0);
            a0 = __builtin_amdgcn_mfma_f32_16x16x32_bf16(alo[0][1], bh1, a0, 0, 0, 0);
            a1 = __builtin_amdgcn_mfma_f32_16x16x32_bf16(alo[1][1], bh1, a1, 0, 0, 0);

            float e2v = e2s[ch * 128 + sub * 16 + c];
            int  code = ch * 128 + sub * 16 + c;
            #pragma unroll
            for (int t = 0; t < 2; ++t) {
                f32x4 av = t ? a1 : a0;
                #pragma unroll
                for (int r = 0; r < 4; ++r) {
                    int i = t * 4 + r;
                    float s = fmaf(-2.f, av[r], e2v);   // dist - x^2 (row-const drop)
                    bool lb = s < best[i];
                    float m = lb ? best[i] : s;
                    second[i] = fminf(second[i], m);
                    best[i]   = fminf(best[i], s);
                    bidx[i]   = lb ? code : bidx[i];
                }
            }
        }
    }

    #pragma unroll
    for (int i = 0; i < 8; ++i) {
        float b = best[i], s2 = second[i];
        int bi = bidx[i];
        #pragma unroll
        for (int m = 1; m < 16; m <<= 1) {
            float ob = __shfl_xor(b, m, 64);
            float os = __shfl_xor(s2, m, 64);
            int   oi = __shfl_xor(bi, m, 64);
            float ns = fminf(fmaxf(b, ob), fminf(s2, os));
            bi = (ob < b || (ob == b && oi < bi)) ? oi : bi;
            b  = fminf(b, ob);
            s2 = ns;
        }
        if (c == 0) {
            int t = i >> 2, r = i & 3;
            int n = rowbase + t * 16 + g * 4 + r;
            out[O_IDX + n] = (float)bi;
            if (s2 - b < MARGIN) {
                int p = atomicAdd(ctr, 1);
                if (p < RCAP) rlist[p] = n;
            }
        }
    }
}

// ---------------------------------------------------------------------------
// K2: fp64 exact argmin for flagged near-ties; fixes index only. One wave
// per candidate.
// ---------------------------------------------------------------------------
__global__ __launch_bounds__(256) void k_refine(
    const float* __restrict__ ze, const float* __restrict__ emb,
    float* __restrict__ out, const int* __restrict__ ctr,
    const int* __restrict__ rlist)
{
    int lane = threadIdx.x & 63;
    int gw   = (blockIdx.x * blockDim.x + threadIdx.x) >> 6;
    int nw   = (gridDim.x * blockDim.x) >> 6;
    int cnt  = *ctr;
    if (cnt > RCAP) cnt = RCAP;

    for (int i = gw; i < cnt; i += nw) {
        int n = rlist[i];
        const float* zp = ze + (size_t)(n >> 12) * CHW + (n & 4095);
        float x[DCV];
        #pragma unroll
        for (int d = 0; d < DCV; ++d) x[d] = zp[(size_t)d * HWN];  // uniform -> broadcast

        double bd = 1e300;
        int    bi = 0;
        #pragma unroll 1
        for (int cc = 0; cc < KCB / 64; ++cc) {
            int k = cc * 64 + lane;
            const float4* eb4 = (const float4*)(emb + k * DCV);
            double a0 = 0.0, a1 = 0.0;
            #pragma unroll
            for (int q = 0; q < DCV / 4; ++q) {
                float4 v = eb4[q];
                double d0 = (double)x[q * 4 + 0] - (double)v.x;
                double d1 = (double)x[q * 4 + 1] - (double)v.y;
                double d2 = (double)x[q * 4 + 2] - (double)v.z;
                double d3 = (double)x[q * 4 + 3] - (double)v.w;
                a0 = fma(d0, d0, a0); a1 = fma(d1, d1, a1);
                a0 = fma(d2, d2, a0); a1 = fma(d3, d3, a1);
            }
            double dist = a0 + a1;
            if (dist < bd || (dist == bd && k < bi)) { bd = dist; bi = k; }
        }
        #pragma unroll
        for (int off = 32; off > 0; off >>= 1) {
            double od = __shfl_xor(bd, off, 64);
            int    oi = __shfl_xor(bi, off, 64);
            if (od < bd || (od == bd && oi < bi)) { bd = od; bi = oi; }
        }
        if (lane == 0) out[O_IDX + n] = (float)bi;
    }
}

// ---------------------------------------------------------------------------
// K3: fused post-pass (single z_e read): z_q_st write (coalesced per-d),
// commitment-loss partials, dw LDS bins -> atomic flush into NEA, counts
// (gidx==0 blocks) -> atomic flush into NCS. Block = (gidx, b).
// ---------------------------------------------------------------------------
__global__ __launch_bounds__(256) void k_post(
    const float* __restrict__ ze, const float* __restrict__ embT,
    float* __restrict__ out, double* __restrict__ loss)
{
    int gidx = blockIdx.x >> 5, b = blockIdx.x & 31;
    __shared__ float acc[8 * KCB];   // [code][dim8]  32 KB
    __shared__ float cnt[KCB];       // 4 KB (gidx==0 only)
    __shared__ float wsum[4];
    for (int i = threadIdx.x; i < 8 * KCB; i += 256) acc[i] = 0.f;
    if (gidx == 0) for (int i = threadIdx.x; i < KCB; i += 256) cnt[i] = 0.f;
    __syncthreads();

    const float* zp  = ze  + (size_t)b * CHW + (size_t)gidx * 8 * HWN;
    float*       zq  = out + O_ZQ + (size_t)b * CHW + (size_t)gidx * 8 * HWN;
    const float* ipf = out + O_IDX + b * HWN;
    const float* eT  = embT + (size_t)gidx * 8 * KCB;

    float lp = 0.f;
    for (int hw = threadIdx.x; hw < HWN; hw += 256) {
        int idx = (int)ipf[hw];
        #pragma unroll
        for (int i = 0; i < 8; ++i) {
            float x = zp[(size_t)i * HWN + hw];
            float e = eT[i * KCB + idx];
            float df = x - e;
            lp = fmaf(df, df, lp);
            zq[(size_t)i * HWN + hw] = x + (e - x);  // straight-through rounding
            atomicAdd(&acc[idx * 8 + i], x);
        }
        if (gidx == 0) atomicAdd(&cnt[idx], 1.f);
    }

    #pragma unroll
    for (int off = 32; off > 0; off >>= 1) lp += __shfl_down(lp, off, 64);
    int lane = threadIdx.x & 63, wid = threadIdx.x >> 6;
    if (lane == 0) wsum[wid] = lp;
    __syncthreads();
    if (threadIdx.x == 0) {
        double s = (double)wsum[0] + wsum[1] + wsum[2] + wsum[3];
        atomicAdd(loss, s);
    }

    for (int j = threadIdx.x; j < 8192; j += 256) {
        float v = acc[j];
        if (v != 0.f) atomicAdd(&out[O_NEA + (j >> 3) * DCV + gidx * 8 + (j & 7)], 0.01f * v);
    }
    if (gidx == 0)
        for (int k = threadIdx.x; k < KCB; k += 256) {
            float cv = cnt[k];
            if (cv != 0.f) atomicAdd(&out[O_NCS + k], 0.01f * cv);
        }
}

// ---------------------------------------------------------------------------
// K4: fused stats+embed: each block redundantly reduces NCS (4 KB) to n,
// then computes its 256 NE outputs. Block 0 also writes the loss scalar.
// ---------------------------------------------------------------------------
__global__ __launch_bounds__(256) void k_fin(
    float* __restrict__ out, const double* __restrict__ loss)
{
    __shared__ float red[4];
    int t = threadIdx.x;
    float s = 0.f;
    #pragma unroll
    for (int q = 0; q < 4; ++q) s += out[O_NCS + t * 4 + q];
    #pragma unroll
    for (int off = 32; off > 0; off >>= 1) s += __shfl_down(s, off, 64);
    int lane = t & 63, wid = t >> 6;
    if (lane == 0) red[wid] = s;
    __syncthreads();
    float n = red[0] + red[1] + red[2] + red[3];

    int j = blockIdx.x * 256 + t;      // 0..65535
    int k = j >> 6;
    float ncs = out[O_NCS + k];
    float sm = (ncs + 1e-5f) / (n + (float)KCB * 1e-5f) * n;
    out[O_NE + j] = out[O_NEA + j] / sm;

    if (blockIdx.x == 0 && t == 0)
        out[O_LOSS] = (float)(0.25 * (*loss) / (double)(NTOT * DCV));
}

// ---------------------------------------------------------------------------
extern "C" void kernel_launch(void* const* d_in, const int* in_sizes, int n_in,
                              void* d_out, int out_size, void* d_ws, size_t ws_size,
                              hipStream_t stream)
{
    const float* ze  = (const float*)d_in[0];
    const float* emb = (const float*)d_in[1];
    const float* cs  = (const float*)d_in[2];
    const float* ea  = (const float*)d_in[3];
    float* out = (float*)d_out;

    char*   w     = (char*)d_ws;
    double* loss  = (double*)(w + W_LOSS);
    int*    ctr   = (int*)(w + W_CTR);
    float*  e2    = (float*)(w + W_E2);
    short*  hiT   = (short*)(w + W_HIT);
    short*  loT   = (short*)(w + W_LOT);
    float*  embT  = (float*)(w + W_EMBT);
    int*    rlist = (int*)(w + W_RLIST);

    k_init  <<<256, 256, 0, stream>>>(emb, ea, cs, out, e2, hiT, loT, embT, loss, ctr);
    k_dist  <<<1024, 256, 0, stream>>>(ze, hiT, loT, e2, out, ctr, rlist);
    k_refine<<<256, 256, 0, stream>>>(ze, emb, out, ctr, rlist);
    k_post  <<<256, 256, 0, stream>>>(ze, embT, out, loss);
    k_fin   <<<256, 256, 0, stream>>>(out, loss);
}

// Round 8
// 238.408 us; speedup vs baseline: 1.3092x; 1.0387x over previous
//
#include <hip/hip_runtime.h>

// Problem constants
#define KCB   1024      // codebook size
#define DCV   64        // code dim
#define HWN   4096      // H*W
#define CHW   262144    // DCV*HWN per batch
#define NTOT  131072    // 32*HWN

// Output offsets (floats), concatenated in reference return order
#define O_ZQ   0
#define O_IDX  8388608
#define O_LOSS 8519680
#define O_NE   8519681
#define O_NCS  8585217
#define O_NEA  8586241

// Workspace byte offsets — TOTAL 790,784 B < 1 MiB (hard limit: round-3 ws
// overflow corrupted the harness's pristine input copy).
#define W_LOSS  0                 // 8 B   double
#define W_CTR   64                // 4 B   int
#define W_E2    256               // 4 KB
#define W_HLT   4352              // 256 KB chunk-major bf16 hi/lo codebook
                                  //   [ch(16)][arr(2)][q(8)][code(64)][8] shorts
#define W_EMBT  266496            // 256 KB transposed codebook [d][code] f32
#define W_RLIST 528640            // 256 KB refine list (cap 65536)
// end = 790784

#define RCAP   65536
// hi/lo bf16 split worst-case pairwise dist error <~1e-3; 0.005 = 5x margin
#define MARGIN 0.005f

typedef __attribute__((ext_vector_type(8))) short short8v;
typedef __attribute__((ext_vector_type(4))) float f32x4;

__device__ __forceinline__ unsigned short rne16(float f) {
    unsigned u = __float_as_uint(f);
    unsigned r = (u + 0x7FFFu + ((u >> 16) & 1u)) >> 16;  // RNE to bf16 bits
    return (unsigned short)r;
}

// ---------------------------------------------------------------------------
// K0: init NEA=0.99*ea, NCS=0.99*cs; e2=||e||^2; chunk-major bf16 hi/lo
// codebook hl; transposed f32 codebook embT[d][code]; zero scalars.
// ---------------------------------------------------------------------------
__global__ __launch_bounds__(256) void k_init(
    const float* __restrict__ emb, const float* __restrict__ ea,
    const float* __restrict__ cs, float* __restrict__ out,
    float* __restrict__ e2, short* __restrict__ hl,
    float* __restrict__ embT, double* __restrict__ loss, int* __restrict__ ctr)
{
    int j = blockIdx.x * 256 + threadIdx.x;   // 0..65535
    out[O_NEA + j] = 0.99f * ea[j];

    // embT[d*1024+code] = emb[code*64+d]; j = code*64+d -> coalesced read
    {
        int code = j >> 6, d = j & 63;
        embT[d * KCB + code] = emb[j];
    }
    if (j < KCB) {
        out[O_NCS + j] = 0.99f * cs[j];
        const float* er = emb + j * DCV;
        float s = 0.f;
        #pragma unroll
        for (int d = 0; d < DCV; ++d) { float v = er[d]; s = fmaf(v, v, s); }
        e2[j] = s;
    }
    if (j < 8192) {
        int code = j >> 3, q = j & 7;
        int ch = code >> 6, lc = code & 63;
        const float* src = emb + code * DCV + q * 8;
        short8v h, l;
        #pragma unroll
        for (int t = 0; t < 8; ++t) {
            float x = src[t];
            unsigned short hb = rne16(x);
            float xh = __uint_as_float(((unsigned)hb) << 16);
            h[t] = (short)hb;
            l[t] = (short)rne16(x - xh);
        }
        *(short8v*)(hl + (size_t)(((ch * 2 + 0) * 8 + q) * 64 + lc) * 8) = h;
        *(short8v*)(hl + (size_t)(((ch * 2 + 1) * 8 + q) * 64 + lc) * 8) = l;
    }
    if (j == 0) { *loss = 0.0; *ctr = 0; }
}

// ---------------------------------------------------------------------------
// K1: MFMA distance argmin with double-buffered async LDS staging.
// Block = 128 rows (4 waves x 32). 16 chunks of 64 codes; per chunk
// 16 KB staged via global_load_lds (width 16) into lds[buf^1] while
// computing lds[buf]; one barrier per chunk. Per 16-code sub: 12 mfma
// (hi*hi, hi*lo, lo*hi over 2 K-halves x 2 row-frags). Near-ties
// (gap < MARGIN) flagged for fp64 refine.
// ---------------------------------------------------------------------------
__global__ __launch_bounds__(256, 2) void k_dist(
    const float* __restrict__ ze, const char* __restrict__ hl,
    const float* __restrict__ e2g, float* __restrict__ out,
    int* __restrict__ ctr, int* __restrict__ rlist)
{
    __shared__ short lds[2][8192];        // 2 x 16 KB: [arr(2)][q(8)][code(64)][8]
    __shared__ float e2s[KCB];            // 4 KB

    int tid  = threadIdx.x;
    int lane = tid & 63, w = tid >> 6;
    int g = lane >> 4, c = lane & 15;

    for (int i = tid; i < KCB; i += 256) e2s[i] = e2g[i];

    // async stage of one 16KB chunk: linear copy, wave w covers 4x1KB slices
    #define STAGE(buf, ch)                                                     \
        {                                                                      \
            _Pragma("unroll")                                                  \
            for (int r = 0; r < 4; ++r) {                                      \
                int off = (r * 4 + w) * 1024 + lane * 16;                      \
                __builtin_amdgcn_global_load_lds(                              \
                    (const __attribute__((address_space(1))) void*)            \
                        (hl + (size_t)(ch) * 16384 + off),                     \
                    (__attribute__((address_space(3))) void*)                  \
                        ((char*)lds[buf] + off),                               \
                    16, 0, 0);                                                 \
            }                                                                  \
        }

    // A-fragments: row = lane&15, k = kh*32 + 8*(lane>>4) + j (same bijection as B)
    int rowbase = blockIdx.x * 128 + w * 32;
    short8v ahi[2][2], alo[2][2];
    #pragma unroll
    for (int t = 0; t < 2; ++t) {
        int n = rowbase + t * 16 + c;
        const float* base = ze + (size_t)(n >> 12) * CHW + (n & 4095);
        #pragma unroll
        for (int kh = 0; kh < 2; ++kh) {
            #pragma unroll
            for (int j = 0; j < 8; ++j) {
                int k = kh * 32 + g * 8 + j;
                float x = base[(size_t)k * HWN];
                unsigned short hb = rne16(x);
                float xh = __uint_as_float(((unsigned)hb) << 16);
                ahi[t][kh][j] = (short)hb;
                alo[t][kh][j] = (short)rne16(x - xh);
            }
        }
    }

    float best[8], second[8];
    int   bidx[8];
    #pragma unroll
    for (int i = 0; i < 8; ++i) { best[i] = 3.4e38f; second[i] = 3.4e38f; bidx[i] = 0; }

    STAGE(0, 0);
    __syncthreads();          // drains vmcnt -> buf0 ready

    int cur = 0;
    for (int ch = 0; ch < 16; ++ch) {
        if (ch < 15) STAGE(cur ^ 1, ch + 1);   // async prefetch next chunk

        const short* L = lds[cur];
        #pragma unroll
        for (int sub = 0; sub < 4; ++sub) {
            int boff = (sub * 16 + c) * 8;
            short8v bh0 = *(const short8v*)&L[(g * 64) * 8 + boff];
            short8v bh1 = *(const short8v*)&L[((4 + g) * 64) * 8 + boff];
            short8v bl0 = *(const short8v*)&L[((8 + g) * 64) * 8 + boff];
            short8v bl1 = *(const short8v*)&L[((12 + g) * 64) * 8 + boff];

            f32x4 a0 = {0.f, 0.f, 0.f, 0.f}, a1 = {0.f, 0.f, 0.f, 0.f};
            a0 = __builtin_amdgcn_mfma_f32_16x16x32_bf16(ahi[0][0], bh0, a0, 0, 0, 0);
            a1 = __builtin_amdgcn_mfma_f32_16x16x32_bf16(ahi[1][0], bh0, a1, 0, 0, 0);
            a0 = __builtin_amdgcn_mfma_f32_16x16x32_bf16(ahi[0][1], bh1, a0, 0, 0, 0);
            a1 = __builtin_amdgcn_mfma_f32_16x16x32_bf16(ahi[1][1], bh1, a1, 0, 0, 0);
            a0 = __builtin_amdgcn_mfma_f32_16x16x32_bf16(ahi[0][0], bl0, a0, 0, 0, 0);
            a1 = __builtin_amdgcn_mfma_f32_16x16x32_bf16(ahi[1][0], bl0, a1, 0, 0, 0);
            a0 = __builtin_amdgcn_mfma_f32_16x16x32_bf16(ahi[0][1], bl1, a0, 0, 0, 0);
            a1 = __builtin_amdgcn_mfma_f32_16x16x32_bf16(ahi[1][1], bl1, a1, 0, 0, 0);
            a0 = __builtin_amdgcn_mfma_f32_16x16x32_bf16(alo[0][0], bh0, a0, 0, 0, 0);
            a1 = __builtin_amdgcn_mfma_f32_16x16x32_bf16(alo[1][0], bh0, a1, 0, 0, 0);
            a0 = __builtin_amdgcn_mfma_f32_16x16x32_bf16(alo[0][1], bh1, a0, 0, 0, 0);
            a1 = __builtin_amdgcn_mfma_f32_16x16x32_bf16(alo[1][1], bh1, a1, 0, 0, 0);

            float e2v = e2s[ch * 64 + sub * 16 + c];
            int  code = ch * 64 + sub * 16 + c;
            #pragma unroll
            for (int t = 0; t < 2; ++t) {
                f32x4 av = t ? a1 : a0;
                #pragma unroll
                for (int r = 0; r < 4; ++r) {
                    int i = t * 4 + r;
                    float s = fmaf(-2.f, av[r], e2v);   // dist - x^2 (row-const drop)
                    bool lb = s < best[i];
                    second[i] = fminf(second[i], fmaxf(best[i], s));
                    best[i]   = fminf(best[i], s);
                    bidx[i]   = lb ? code : bidx[i];
                }
            }
        }
        __syncthreads();      // next buffer ready; current safe to overwrite
        cur ^= 1;
    }

    #pragma unroll
    for (int i = 0; i < 8; ++i) {
        float b = best[i], s2 = second[i];
        int bi = bidx[i];
        #pragma unroll
        for (int m = 1; m < 16; m <<= 1) {
            float ob = __shfl_xor(b, m, 64);
            float os = __shfl_xor(s2, m, 64);
            int   oi = __shfl_xor(bi, m, 64);
            float ns = fminf(fmaxf(b, ob), fminf(s2, os));
            bi = (ob < b || (ob == b && oi < bi)) ? oi : bi;
            b  = fminf(b, ob);
            s2 = ns;
        }
        if (c == 0) {
            int t = i >> 2, r = i & 3;
            int n = rowbase + t * 16 + g * 4 + r;
            out[O_IDX + n] = (float)bi;
            if (s2 - b < MARGIN) {
                int p = atomicAdd(ctr, 1);
                if (p < RCAP) rlist[p] = n;
            }
        }
    }
    #undef STAGE
}

// ---------------------------------------------------------------------------
// K2: fp64 exact argmin for flagged near-ties; fixes index only. One wave
// per candidate.
// ---------------------------------------------------------------------------
__global__ __launch_bounds__(256) void k_refine(
    const float* __restrict__ ze, const float* __restrict__ emb,
    float* __restrict__ out, const int* __restrict__ ctr,
    const int* __restrict__ rlist)
{
    int lane = threadIdx.x & 63;
    int gw   = (blockIdx.x * blockDim.x + threadIdx.x) >> 6;
    int nw   = (gridDim.x * blockDim.x) >> 6;
    int cnt  = *ctr;
    if (cnt > RCAP) cnt = RCAP;

    for (int i = gw; i < cnt; i += nw) {
        int n = rlist[i];
        const float* zp = ze + (size_t)(n >> 12) * CHW + (n & 4095);
        float x[DCV];
        #pragma unroll
        for (int d = 0; d < DCV; ++d) x[d] = zp[(size_t)d * HWN];  // uniform -> broadcast

        double bd = 1e300;
        int    bi = 0;
        #pragma unroll 1
        for (int cc = 0; cc < KCB / 64; ++cc) {
            int k = cc * 64 + lane;
            const float4* eb4 = (const float4*)(emb + k * DCV);
            double a0 = 0.0, a1 = 0.0;
            #pragma unroll
            for (int q = 0; q < DCV / 4; ++q) {
                float4 v = eb4[q];
                double d0 = (double)x[q * 4 + 0] - (double)v.x;
                double d1 = (double)x[q * 4 + 1] - (double)v.y;
                double d2 = (double)x[q * 4 + 2] - (double)v.z;
                double d3 = (double)x[q * 4 + 3] - (double)v.w;
                a0 = fma(d0, d0, a0); a1 = fma(d1, d1, a1);
                a0 = fma(d2, d2, a0); a1 = fma(d3, d3, a1);
            }
            double dist = a0 + a1;
            if (dist < bd || (dist == bd && k < bi)) { bd = dist; bi = k; }
        }
        #pragma unroll
        for (int off = 32; off > 0; off >>= 1) {
            double od = __shfl_xor(bd, off, 64);
            int    oi = __shfl_xor(bi, off, 64);
            if (od < bd || (od == bd && oi < bi)) { bd = od; bi = oi; }
        }
        if (lane == 0) out[O_IDX + n] = (float)bi;
    }
}

// ---------------------------------------------------------------------------
// K3: fused post-pass (single z_e read): z_q_st write (coalesced per-d),
// commitment-loss partials, dw LDS bins -> atomic flush into NEA, counts
// (gidx==0 blocks) -> atomic flush into NCS. Block = (gidx, b).
// ---------------------------------------------------------------------------
__global__ __launch_bounds__(256) void k_post(
    const float* __restrict__ ze, const float* __restrict__ embT,
    float* __restrict__ out, double* __restrict__ loss)
{
    int gidx = blockIdx.x >> 5, b = blockIdx.x & 31;
    __shared__ float acc[8 * KCB];   // [code][dim8]  32 KB
    __shared__ float cnt[KCB];       // 4 KB (gidx==0 only)
    __shared__ float wsum[4];
    for (int i = threadIdx.x; i < 8 * KCB; i += 256) acc[i] = 0.f;
    if (gidx == 0) for (int i = threadIdx.x; i < KCB; i += 256) cnt[i] = 0.f;
    __syncthreads();

    const float* zp  = ze  + (size_t)b * CHW + (size_t)gidx * 8 * HWN;
    float*       zq  = out + O_ZQ + (size_t)b * CHW + (size_t)gidx * 8 * HWN;
    const float* ipf = out + O_IDX + b * HWN;
    const float* eT  = embT + (size_t)gidx * 8 * KCB;

    float lp = 0.f;
    for (int hw = threadIdx.x; hw < HWN; hw += 256) {
        int idx = (int)ipf[hw];
        #pragma unroll
        for (int i = 0; i < 8; ++i) {
            float x = zp[(size_t)i * HWN + hw];
            float e = eT[i * KCB + idx];
            float df = x - e;
            lp = fmaf(df, df, lp);
            zq[(size_t)i * HWN + hw] = x + (e - x);  // straight-through rounding
            atomicAdd(&acc[idx * 8 + i], x);
        }
        if (gidx == 0) atomicAdd(&cnt[idx], 1.f);
    }

    #pragma unroll
    for (int off = 32; off > 0; off >>= 1) lp += __shfl_down(lp, off, 64);
    int lane = threadIdx.x & 63, wid = threadIdx.x >> 6;
    if (lane == 0) wsum[wid] = lp;
    __syncthreads();
    if (threadIdx.x == 0) {
        double s = (double)wsum[0] + wsum[1] + wsum[2] + wsum[3];
        atomicAdd(loss, s);
    }

    for (int j = threadIdx.x; j < 8192; j += 256) {
        float v = acc[j];
        if (v != 0.f) atomicAdd(&out[O_NEA + (j >> 3) * DCV + gidx * 8 + (j & 7)], 0.01f * v);
    }
    if (gidx == 0)
        for (int k = threadIdx.x; k < KCB; k += 256) {
            float cv = cnt[k];
            if (cv != 0.f) atomicAdd(&out[O_NCS + k], 0.01f * cv);
        }
}

// ---------------------------------------------------------------------------
// K4: fused stats+embed: each block redundantly reduces NCS (4 KB) to n,
// then computes its 256 NE outputs. Block 0 also writes the loss scalar.
// ---------------------------------------------------------------------------
__global__ __launch_bounds__(256) void k_fin(
    float* __restrict__ out, const double* __restrict__ loss)
{
    __shared__ float red[4];
    int t = threadIdx.x;
    float s = 0.f;
    #pragma unroll
    for (int q = 0; q < 4; ++q) s += out[O_NCS + t * 4 + q];
    #pragma unroll
    for (int off = 32; off > 0; off >>= 1) s += __shfl_down(s, off, 64);
    int lane = t & 63, wid = t >> 6;
    if (lane == 0) red[wid] = s;
    __syncthreads();
    float n = red[0] + red[1] + red[2] + red[3];

    int j = blockIdx.x * 256 + t;      // 0..65535
    int k = j >> 6;
    float ncs = out[O_NCS + k];
    float sm = (ncs + 1e-5f) / (n + (float)KCB * 1e-5f) * n;
    out[O_NE + j] = out[O_NEA + j] / sm;

    if (blockIdx.x == 0 && t == 0)
        out[O_LOSS] = (float)(0.25 * (*loss) / (double)(NTOT * DCV));
}

// ---------------------------------------------------------------------------
extern "C" void kernel_launch(void* const* d_in, const int* in_sizes, int n_in,
                              void* d_out, int out_size, void* d_ws, size_t ws_size,
                              hipStream_t stream)
{
    const float* ze  = (const float*)d_in[0];
    const float* emb = (const float*)d_in[1];
    const float* cs  = (const float*)d_in[2];
    const float* ea  = (const float*)d_in[3];
    float* out = (float*)d_out;

    char*   w     = (char*)d_ws;
    double* loss  = (double*)(w + W_LOSS);
    int*    ctr   = (int*)(w + W_CTR);
    float*  e2    = (float*)(w + W_E2);
    short*  hl    = (short*)(w + W_HLT);
    float*  embT  = (float*)(w + W_EMBT);
    int*    rlist = (int*)(w + W_RLIST);

    k_init  <<<256, 256, 0, stream>>>(emb, ea, cs, out, e2, hl, embT, loss, ctr);
    k_dist  <<<1024, 256, 0, stream>>>(ze, (const char*)hl, e2, out, ctr, rlist);
    k_refine<<<256, 256, 0, stream>>>(ze, emb, out, ctr, rlist);
    k_post  <<<256, 256, 0, stream>>>(ze, embT, out, loss);
    k_fin   <<<256, 256, 0, stream>>>(out, loss);
}